// Round 3
// baseline (247.265 us; speedup 1.0000x reference)
//
#include <hip/hip_runtime.h>
#include <hip/hip_bf16.h>

#define EPS 1e-8f
#define B_  16
#define CIN 256
#define COUT 256
#define HW 64

typedef __bf16 bf16x8 __attribute__((ext_vector_type(8)));
typedef float  f32x4  __attribute__((ext_vector_type(4)));

__device__ __forceinline__ void async16(void* lds, const void* g) {
    __builtin_amdgcn_global_load_lds(
        (const __attribute__((address_space(1))) unsigned int*)g,
        (__attribute__((address_space(3))) unsigned int*)lds,
        16, 0, 0);
}

__device__ __forceinline__ uint pack2(float lo, float hi) {
    __bf16 a = (__bf16)lo, b = (__bf16)hi;
    unsigned short ua = __builtin_bit_cast(unsigned short, a);
    unsigned short ub = __builtin_bit_cast(unsigned short, b);
    return ((uint)ub << 16) | (uint)ua;
}

// ================= fused prep kernel =================
// bid 0..255    : wmod role (co = bid), self-contained stats, loops b=0..15
// bid 256       : zrow zero-fill (36,864 B)
// bid 257..1280 : x transpose role (idx = bid-257: row = idx&63, b = idx>>6)
// wfull layout: [b][tap][cc=ci>>5][co][ci&31]  (conv A-frag = one contiguous 1 KB)
// xbf layout:   [b][row][col 0..63][ci]  (bf16, no halo cols)
__global__ __launch_bounds__(256) void prep_kernel(const float* __restrict__ x,
                                                   const float* __restrict__ s,
                                                   const float* __restrict__ w,
                                                   __bf16* __restrict__ xbf,
                                                   __bf16* __restrict__ wfull,
                                                   __bf16* __restrict__ zrow) {
    __shared__ uint xsd[64 * 160];   // 40,960 B (x-transpose role)
    __shared__ float red[8];
    const int bid = blockIdx.x;
    const int t   = threadIdx.x;

    if (bid == 256) {                 // ---- zrow zero role ----
        uint4 z = make_uint4(0, 0, 0, 0);
        uint4* zp = (uint4*)zrow;
#pragma unroll
        for (int k = 0; k < 9; ++k) zp[k * 256 + t] = z;
        return;
    }

    if (bid < 256) {                  // ---- wmod role (one co, all b) ----
        const int co = bid;
        const int ci = t;
        const int lane = t & 63, wid = t >> 6;
        // ssum = sum(s^2) over all 4096 (redundant per block, s is L2-hot)
        float as = 0.f;
#pragma unroll
        for (int k = 0; k < 16; ++k) { float sv = s[k * 256 + t]; as += sv * sv; }
        // w row + per-ci tap-sum q
        const float* wp = w + ((size_t)co * CIN + ci) * 9;
        float wv[9];
        float q = 0.f;
#pragma unroll
        for (int tp = 0; tp < 9; ++tp) { wv[tp] = wp[tp]; q += wv[tp] * wv[tp]; }
        // dual block-reduce: as -> ssum, q -> Sw
        float a = as, qq = q;
        for (int off = 32; off > 0; off >>= 1) {
            a  += __shfl_down(a,  off, 64);
            qq += __shfl_down(qq, off, 64);
        }
        if (lane == 0) { red[wid] = a; red[4 + wid] = qq; }
        __syncthreads();
        const float ssum = red[0] + red[1] + red[2] + red[3];
        const float Sw   = red[4] + red[5] + red[6] + red[7];
        const float sn2  = (float)(B_ * CIN) / ssum;
        const float wn   = rsqrtf(Sw / 2304.f);
        const float wn2sn2 = wn * wn * sn2;
        const float wsn  = wn * sqrtf(sn2);

        for (int b = 0; b < B_; ++b) {
            const float sv = s[b * CIN + ci];
            float v = sv * sv * q;
            for (int off = 32; off > 0; off >>= 1) v += __shfl_down(v, off, 64);
            __syncthreads();                       // red reads from prev iter done
            if (lane == 0) red[wid] = v;
            __syncthreads();
            const float S = red[0] + red[1] + red[2] + red[3];
            const float coef = wsn * rsqrtf(wn2sn2 * S + EPS);
            const float sc = sv * coef;
            const size_t obase = ((size_t)b * 9) * 65536 + (size_t)(ci >> 5) * 8192
                               + (size_t)co * 32 + (ci & 31);
#pragma unroll
            for (int tap = 0; tap < 9; ++tap)
                wfull[obase + (size_t)tap * 65536] = (__bf16)(wv[tap] * sc);
        }
        return;
    }

    // ---- x transpose role: fp32 NCHW -> bf16 [b][row][col][ci] ----
    // LDS dword grid [c=0..63][160]; ci-pair j at dword c*160 + j + (j>>2) (skew).
    const int idx = bid - 257;
    const int row = idx & 63;
    const int b   = idx >> 6;
    const float* xbase = x + ((size_t)b * CIN * HW + row) * HW;
#pragma unroll
    for (int k = 0; k < 8; ++k) {
        int p   = k * 256 + t;
        int ci2 = p >> 4;                 // ci pair 0..127
        int c4  = (p & 15) * 4;
        const float* src = xbase + (size_t)(2 * ci2) * (HW * HW) + c4;
        float4 v0 = *(const float4*)src;
        float4 v1 = *(const float4*)(src + HW * HW);
        const int dj = ci2 + (ci2 >> 2);
#pragma unroll
        for (int i = 0; i < 4; ++i)
            xsd[(c4 + i) * 160 + dj] = pack2((&v0.x)[i], (&v1.x)[i]);
    }
    __syncthreads();
    __bf16* orow = xbf + (((size_t)b * HW + row) * 64) * CIN;
#pragma unroll
    for (int k = 0; k < 8; ++k) {
        int o   = k * 256 + t;
        int col = o >> 5;
        int u   = o & 31;
        const uint* rp = &xsd[col * 160 + 5 * u];
        uint4 vv; vv.x = rp[0]; vv.y = rp[1]; vv.z = rp[2]; vv.w = rp[3];
        *(uint4*)&orow[(size_t)col * CIN + u * 8] = vv;
    }
}

// ================= MFMA implicit-GEMM conv, v6 =================
// grid 1024 (XCD-affine: b = bid&7 + 8*(bid>=512), row = (bid>>3)&63), 4 waves.
// v6: bank-conflict-free LDS x tile.
//   Per buf: 1024 slots of 16B, chunk i (= ci-octet qq) spans slots [i*256, i*256+256).
//   Physical slot for logical (qq, rem = irow*66+col) is qq*256 + (rem ^ qq):
//   the low-2-bit XOR spreads the four q-groups (which share banks at stride
//   4096 B) onto distinct banks. Producer pre-swizzles the GLOBAL source
//   (dest stays linear for global_load_lds); consumer XORs the read address.
// A (wfull) prefetched one tap ahead + across cc; B prefetched one tap ahead.
__global__ __launch_bounds__(256, 3) void conv_mfma3(const __bf16* __restrict__ xbf,
                                                     const __bf16* __restrict__ zrow,
                                                     const __bf16* __restrict__ wfull,
                                                     float* __restrict__ out) {
    __shared__ __attribute__((aligned(16))) __bf16 xs[2][1024 * 8];   // 2 x 16,384 B

    const int bid = blockIdx.x;
    const int b    = (bid & 7) + ((bid >= 512) ? 8 : 0);
    const int row0 = (bid >> 3) & 63;
    const int t = threadIdx.x;
    const int wy = t >> 6, lane = t & 63;
    const int m16 = lane & 15, q = lane >> 4;
    const int qx = q << 8;                  // q*256 slot base for B reads

    // staging sources: 4 async16 per thread; dest slot i*256+t (linear),
    // logical (qq=i, rem = t ^ i) -> source pre-swizzled.
    const __bf16* gsrc[4];
#pragma unroll
    for (int i = 0; i < 4; ++i) {
        int rem  = t ^ i;
        int irow = rem / 66;
        int col  = rem - irow * 66;
        int gr   = row0 - 1 + irow;
        const __bf16* g;
        if (rem >= 198) {
            g = zrow;
        } else if ((unsigned)gr < 64u && col != 0 && col != 65) {
            g = xbf + (((size_t)b * HW + gr) * 64 + (col - 1)) * CIN + i * 8;
        } else {
            g = zrow + col * CIN + i * 8;   // zero halo pool
        }
        gsrc[i] = g;
    }

    // prologue: stage chunk 0 into buf 0
#pragma unroll
    for (int i = 0; i < 4; ++i)
        async16((char*)xs[0] + (i * 256 + t) * 16, gsrc[i]);

    f32x4 acc[4][4] = {};
    const __bf16* abase = wfull + (size_t)b * 589824
                        + (size_t)(wy * 64 + m16) * 32 + q * 8;

    bf16x8 afc[4], bfc[4];
#pragma unroll
    for (int i = 0; i < 4; ++i)
        afc[i] = *(const bf16x8*)(abase + i * 512);    // cc=0, tap=0

    for (int cc = 0; cc < 8; ++cc) {
        const __bf16* wb = abase + (size_t)cc * 8192;
        __syncthreads();                       // drains chunk-cc staging
        if (cc < 7) {
#pragma unroll
            for (int i = 0; i < 4; ++i)
                async16((char*)xs[(cc + 1) & 1] + (i * 256 + t) * 16, gsrc[i] + cc * 32 + 32);
        }
        const __bf16* xcur = xs[cc & 1];
        {   // B tap 0 (dr=0, dc=0): rem = m16 + j*16
#pragma unroll
            for (int j = 0; j < 4; ++j) {
                int phys = qx + ((m16 + j * 16) ^ q);
                bfc[j] = *(const bf16x8*)&xcur[phys * 8];
            }
        }
#pragma unroll
        for (int tap = 0; tap < 9; ++tap) {
            bf16x8 afn[4], bfn[4];
            if (tap < 8) {
#pragma unroll
                for (int i = 0; i < 4; ++i)
                    afn[i] = *(const bf16x8*)(wb + (size_t)(tap + 1) * 65536 + i * 512);
                const int dr = (tap + 1) / 3, dc = (tap + 1) % 3;
                const int rembase = dr * 66 + m16 + dc;
#pragma unroll
                for (int j = 0; j < 4; ++j) {
                    int phys = qx + ((rembase + j * 16) ^ q);
                    bfn[j] = *(const bf16x8*)&xcur[phys * 8];
                }
            } else if (cc < 7) {
                // prefetch next cc's tap 0 A across the barrier
#pragma unroll
                for (int i = 0; i < 4; ++i)
                    afn[i] = *(const bf16x8*)(wb + 8192 + i * 512);
            }
            __builtin_amdgcn_s_setprio(1);
#pragma unroll
            for (int i = 0; i < 4; ++i)
#pragma unroll
                for (int j = 0; j < 4; ++j)
                    acc[i][j] = __builtin_amdgcn_mfma_f32_16x16x32_bf16(afc[i], bfc[j], acc[i][j], 0, 0, 0);
            __builtin_amdgcn_s_setprio(0);
            if (tap < 8) {
#pragma unroll
                for (int i = 0; i < 4; ++i) afc[i] = afn[i];
#pragma unroll
                for (int j = 0; j < 4; ++j) bfc[j] = bfn[j];
            } else if (cc < 7) {
#pragma unroll
                for (int i = 0; i < 4; ++i) afc[i] = afn[i];
            }
        }
    }

    // epilogue: D col = lane&15 (pixel), row = q*4+reg (co)
#pragma unroll
    for (int i = 0; i < 4; ++i) {
        const int cobase = wy * 64 + i * 16 + q * 4;
#pragma unroll
        for (int reg = 0; reg < 4; ++reg) {
            float* op = out + ((size_t)b * COUT + (cobase + reg)) * (HW * HW) + row0 * HW;
#pragma unroll
            for (int j = 0; j < 4; ++j)
                op[j * 16 + m16] = acc[i][j][reg];
        }
    }
}

extern "C" void kernel_launch(void* const* d_in, const int* in_sizes, int n_in,
                              void* d_out, int out_size, void* d_ws, size_t ws_size,
                              hipStream_t stream) {
    const float* x = (const float*)d_in[0];
    const float* s = (const float*)d_in[1];
    const float* w = (const float*)d_in[2];
    float* out = (float*)d_out;

    float* ws = (float*)d_ws;
    __bf16* wfull = (__bf16*)(ws + 70656);     // 18,874,368 B
    __bf16* zrow  = (__bf16*)(ws + 4789248);   // 36,864 B zero pool
    __bf16* xbf   = (__bf16*)(ws + 4798464);   // 33,554,432 B

    prep_kernel<<<1281, 256, 0, stream>>>(x, s, w, xbf, wfull, zrow);
    conv_mfma3<<<1024, 256, 0, stream>>>(xbf, zrow, wfull, out);
}

// Round 4
// 211.186 us; speedup vs baseline: 1.1708x; 1.1708x over previous
//
#include <hip/hip_runtime.h>
#include <hip/hip_bf16.h>

#define EPS 1e-8f
#define B_  16
#define CIN 256
#define COUT 256
#define HW 64

typedef __bf16 bf16x8 __attribute__((ext_vector_type(8)));
typedef float  f32x4  __attribute__((ext_vector_type(4)));

__device__ __forceinline__ void async16(void* lds, const void* g) {
    __builtin_amdgcn_global_load_lds(
        (const __attribute__((address_space(1))) unsigned int*)g,
        (__attribute__((address_space(3))) unsigned int*)lds,
        16, 0, 0);
}

__device__ __forceinline__ uint pack2(float lo, float hi) {
    __bf16 a = (__bf16)lo, b = (__bf16)hi;
    unsigned short ua = __builtin_bit_cast(unsigned short, a);
    unsigned short ub = __builtin_bit_cast(unsigned short, b);
    return ((uint)ub << 16) | (uint)ua;
}

// ================= fused prep kernel (role-ordered) =================
// bid 0..1023   : x transpose role (row = bid&63, b = bid>>6)  -- launches FIRST
// bid 1024      : zrow zero-fill (36,864 B)
// bid 1025..1280: wmod role (co = bid-1025)                    -- launches LAST
//   (wmod last => wfull, conv's 64x-reused operand, is freshest in L2 at conv start)
// wfull layout: [b][tap][cc=ci>>5][co][ci&31]  (conv A-frag = one contiguous 1 KB)
// xbf layout:   [b][row][col 0..63][ci]  (bf16, no halo cols)
__global__ __launch_bounds__(256) void prep_kernel(const float* __restrict__ x,
                                                   const float* __restrict__ s,
                                                   const float* __restrict__ w,
                                                   __bf16* __restrict__ xbf,
                                                   __bf16* __restrict__ wfull,
                                                   __bf16* __restrict__ zrow) {
    __shared__ uint xsd[64 * 160];   // 40,960 B (transpose role)
    __shared__ float red[8];
    const int bid = blockIdx.x;
    const int t   = threadIdx.x;

    if (bid == 1024) {                // ---- zrow zero role ----
        uint4 z = make_uint4(0, 0, 0, 0);
        uint4* zp = (uint4*)zrow;
#pragma unroll
        for (int k = 0; k < 9; ++k) zp[k * 256 + t] = z;
        return;
    }

    if (bid > 1024) {                 // ---- wmod role (one co, all b) ----
        const int co = bid - 1025;
        const int ci = t;
        const int lane = t & 63, wid = t >> 6;
        float as = 0.f;
#pragma unroll
        for (int k = 0; k < 16; ++k) { float sv = s[k * 256 + t]; as += sv * sv; }
        const float* wp = w + ((size_t)co * CIN + ci) * 9;
        float wv[9];
        float q = 0.f;
#pragma unroll
        for (int tp = 0; tp < 9; ++tp) { wv[tp] = wp[tp]; q += wv[tp] * wv[tp]; }
        float a = as, qq = q;
        for (int off = 32; off > 0; off >>= 1) {
            a  += __shfl_down(a,  off, 64);
            qq += __shfl_down(qq, off, 64);
        }
        if (lane == 0) { red[wid] = a; red[4 + wid] = qq; }
        __syncthreads();
        const float ssum = red[0] + red[1] + red[2] + red[3];
        const float Sw   = red[4] + red[5] + red[6] + red[7];
        const float sn2  = (float)(B_ * CIN) / ssum;
        const float wn   = rsqrtf(Sw / 2304.f);
        const float wn2sn2 = wn * wn * sn2;
        const float wsn  = wn * sqrtf(sn2);

        for (int b = 0; b < B_; ++b) {
            const float sv = s[b * CIN + ci];
            float v = sv * sv * q;
            for (int off = 32; off > 0; off >>= 1) v += __shfl_down(v, off, 64);
            __syncthreads();
            if (lane == 0) red[wid] = v;
            __syncthreads();
            const float S = red[0] + red[1] + red[2] + red[3];
            const float coef = wsn * rsqrtf(wn2sn2 * S + EPS);
            const float sc = sv * coef;
            const size_t obase = ((size_t)b * 9) * 65536 + (size_t)(ci >> 5) * 8192
                               + (size_t)co * 32 + (ci & 31);
#pragma unroll
            for (int tap = 0; tap < 9; ++tap)
                wfull[obase + (size_t)tap * 65536] = (__bf16)(wv[tap] * sc);
        }
        return;
    }

    // ---- x transpose role: fp32 NCHW -> bf16 [b][row][col][ci] ----
    const int row = bid & 63;
    const int b   = bid >> 6;
    const float* xbase = x + ((size_t)b * CIN * HW + row) * HW;
#pragma unroll
    for (int k = 0; k < 8; ++k) {
        int p   = k * 256 + t;
        int ci2 = p >> 4;
        int c4  = (p & 15) * 4;
        const float* src = xbase + (size_t)(2 * ci2) * (HW * HW) + c4;
        float4 v0 = *(const float4*)src;
        float4 v1 = *(const float4*)(src + HW * HW);
        const int dj = ci2 + (ci2 >> 2);
#pragma unroll
        for (int i = 0; i < 4; ++i)
            xsd[(c4 + i) * 160 + dj] = pack2((&v0.x)[i], (&v1.x)[i]);
    }
    __syncthreads();
    __bf16* orow = xbf + (((size_t)b * HW + row) * 64) * CIN;
#pragma unroll
    for (int k = 0; k < 8; ++k) {
        int o   = k * 256 + t;
        int col = o >> 5;
        int u   = o & 31;
        const uint* rp = &xsd[col * 160 + 5 * u];
        uint4 vv; vv.x = rp[0]; vv.y = rp[1]; vv.z = rp[2]; vv.w = rp[3];
        *(uint4*)&orow[(size_t)col * CIN + u * 8] = vv;
    }
}

// ================= MFMA implicit-GEMM conv, v7 =================
// Round-2 v5 structure (proven 99.6 us) + A-prefetch depth 2:
// wfull loads are L2-hit (~200-450 cy) but one tap is only ~80-160 cy of MFMA,
// so a 1-tap lead stalls every tap. af0/af1/af2 rotating window gives a 2-tap
// lead, crossing the cc boundary (next cc taps 0,1 prefetched at taps 7,8).
// LDS x tile (per buf): 800 slots of 16B: slot = qq*200 + irow*66 + col.
__global__ __launch_bounds__(256, 3) void conv_mfma3(const __bf16* __restrict__ xbf,
                                                     const __bf16* __restrict__ zrow,
                                                     const __bf16* __restrict__ wfull,
                                                     float* __restrict__ out) {
    __shared__ __attribute__((aligned(16))) __bf16 xs[2][800 * 8];   // 2 x 12800 B

    const int bid = blockIdx.x;
    const int b    = (bid & 7) + ((bid >= 512) ? 8 : 0);
    const int row0 = (bid >> 3) & 63;
    const int t = threadIdx.x;
    const int wy = t >> 6, lane = t & 63;
    const int m16 = lane & 15, q = lane >> 4;

    const __bf16* gsrc[4];
    unsigned ldsoff[4];
    bool val[4];
#pragma unroll
    for (int i = 0; i < 4; ++i) {
        int slot = i * 256 + t;
        val[i] = slot < 800;
        int qq  = slot / 200;
        int rem = slot - qq * 200;
        int irow = rem / 66;
        int col  = rem - irow * 66;
        int gr = row0 - 1 + irow;
        const __bf16* g;
        if (!val[i] || rem >= 198) {
            g = zrow;
        } else if ((unsigned)gr < 64u && col != 0 && col != 65) {
            g = xbf + (((size_t)b * HW + gr) * 64 + (col - 1)) * CIN + qq * 8;
        } else {
            g = zrow + col * CIN + qq * 8;    // zero halo pool
        }
        gsrc[i] = g;
        ldsoff[i] = (unsigned)slot * 16;
    }

    // prologue: stage chunk 0 into buf 0
#pragma unroll
    for (int i = 0; i < 4; ++i)
        if (val[i]) async16((char*)xs[0] + ldsoff[i], gsrc[i]);

    f32x4 acc[4][4] = {};
    const __bf16* abase = wfull + (size_t)b * 589824
                        + (size_t)(wy * 64 + m16) * 32 + q * 8;

    bf16x8 af0[4], af1[4], bfc[4];
#pragma unroll
    for (int i = 0; i < 4; ++i) {
        af0[i] = *(const bf16x8*)(abase + i * 512);            // cc=0, tap 0
        af1[i] = *(const bf16x8*)(abase + 65536 + i * 512);    // cc=0, tap 1
    }

    for (int cc = 0; cc < 8; ++cc) {
        const __bf16* wb = abase + (size_t)cc * 8192;
        __syncthreads();                       // drains chunk-cc staging
        if (cc < 7) {
#pragma unroll
            for (int i = 0; i < 4; ++i)
                if (val[i]) async16((char*)xs[(cc + 1) & 1] + ldsoff[i], gsrc[i] + cc * 32 + 32);
        }
        const __bf16* xcur = xs[cc & 1];
        {   // B tap 0 (dr=0, dc=0)
            const int rb = (q * 200 + m16) * 8;
#pragma unroll
            for (int j = 0; j < 4; ++j)
                bfc[j] = *(const bf16x8*)&xcur[rb + j * 128];
        }
#pragma unroll
        for (int tap = 0; tap < 9; ++tap) {
            bf16x8 af2[4], bfn[4];
            // A prefetch for tap+2 (2-tap lead), crossing cc boundary
            if (tap < 7) {
#pragma unroll
                for (int i = 0; i < 4; ++i)
                    af2[i] = *(const bf16x8*)(wb + (size_t)(tap + 2) * 65536 + i * 512);
            } else if (cc < 7) {
#pragma unroll
                for (int i = 0; i < 4; ++i)
                    af2[i] = *(const bf16x8*)(wb + 8192 + (size_t)(tap - 7) * 65536 + i * 512);
            }
            // B prefetch for tap+1
            if (tap < 8) {
                const int dr = (tap + 1) / 3, dc = (tap + 1) % 3;
                const int rb = (q * 200 + dr * 66 + m16 + dc) * 8;
#pragma unroll
                for (int j = 0; j < 4; ++j)
                    bfn[j] = *(const bf16x8*)&xcur[rb + j * 128];
            }
            __builtin_amdgcn_s_setprio(1);
#pragma unroll
            for (int i = 0; i < 4; ++i)
#pragma unroll
                for (int j = 0; j < 4; ++j)
                    acc[i][j] = __builtin_amdgcn_mfma_f32_16x16x32_bf16(af0[i], bfc[j], acc[i][j], 0, 0, 0);
            __builtin_amdgcn_s_setprio(0);
            // rotate windows
#pragma unroll
            for (int i = 0; i < 4; ++i) af0[i] = af1[i];
            if (tap < 7 || cc < 7) {
#pragma unroll
                for (int i = 0; i < 4; ++i) af1[i] = af2[i];
            }
            if (tap < 8) {
#pragma unroll
                for (int j = 0; j < 4; ++j) bfc[j] = bfn[j];
            }
        }
    }

    // epilogue: D col = lane&15 (pixel), row = q*4+reg (co)
#pragma unroll
    for (int i = 0; i < 4; ++i) {
        const int cobase = wy * 64 + i * 16 + q * 4;
#pragma unroll
        for (int reg = 0; reg < 4; ++reg) {
            float* op = out + ((size_t)b * COUT + (cobase + reg)) * (HW * HW) + row0 * HW;
#pragma unroll
            for (int j = 0; j < 4; ++j)
                op[j * 16 + m16] = acc[i][j][reg];
        }
    }
}

extern "C" void kernel_launch(void* const* d_in, const int* in_sizes, int n_in,
                              void* d_out, int out_size, void* d_ws, size_t ws_size,
                              hipStream_t stream) {
    const float* x = (const float*)d_in[0];
    const float* s = (const float*)d_in[1];
    const float* w = (const float*)d_in[2];
    float* out = (float*)d_out;

    float* ws = (float*)d_ws;
    __bf16* wfull = (__bf16*)(ws + 70656);     // 18,874,368 B
    __bf16* zrow  = (__bf16*)(ws + 4789248);   // 36,864 B zero pool
    __bf16* xbf   = (__bf16*)(ws + 4798464);   // 33,554,432 B

    prep_kernel<<<1281, 256, 0, stream>>>(x, s, w, xbf, wfull, zrow);
    conv_mfma3<<<1024, 256, 0, stream>>>(xbf, zrow, wfull, out);
}

// Round 6
// 181.099 us; speedup vs baseline: 1.3654x; 1.1661x over previous
//
#include <hip/hip_runtime.h>
#include <hip/hip_bf16.h>

#define EPS 1e-8f
#define B_  16
#define CIN 256
#define COUT 256
#define HW 64

typedef __bf16 bf16x8 __attribute__((ext_vector_type(8)));
typedef float  f32x4  __attribute__((ext_vector_type(4)));

__device__ __forceinline__ void async16(void* lds, const void* g) {
    __builtin_amdgcn_global_load_lds(
        (const __attribute__((address_space(1))) unsigned int*)g,
        (__attribute__((address_space(3))) unsigned int*)lds,
        16, 0, 0);
}

__device__ __forceinline__ uint pack2(float lo, float hi) {
    __bf16 a = (__bf16)lo, b = (__bf16)hi;
    unsigned short ua = __builtin_bit_cast(unsigned short, a);
    unsigned short ub = __builtin_bit_cast(unsigned short, b);
    return ((uint)ub << 16) | (uint)ua;
}

// ================= fused prep kernel (role-ordered) =================
// bid 0..1023   : x transpose role (row = bid&63, b = bid>>6)  -- launches FIRST
// bid 1024      : zrow zero-fill (36,864 B)
// bid 1025..1280: wmod role (co = bid-1025)                    -- launches LAST
// wfull layout: [b][tap][cc=ci>>5][co][ci&31]  (conv A-frag = one contiguous 1 KB)
// xbf layout:   [b][row][col 0..63][ci]  (bf16, no halo cols)
__global__ __launch_bounds__(256) void prep_kernel(const float* __restrict__ x,
                                                   const float* __restrict__ s,
                                                   const float* __restrict__ w,
                                                   __bf16* __restrict__ xbf,
                                                   __bf16* __restrict__ wfull,
                                                   __bf16* __restrict__ zrow) {
    __shared__ uint xsd[64 * 160];   // 40,960 B (transpose role)
    __shared__ float red[8];
    const int bid = blockIdx.x;
    const int t   = threadIdx.x;

    if (bid == 1024) {                // ---- zrow zero role ----
        uint4 z = make_uint4(0, 0, 0, 0);
        uint4* zp = (uint4*)zrow;
#pragma unroll
        for (int k = 0; k < 9; ++k) zp[k * 256 + t] = z;
        return;
    }

    if (bid > 1024) {                 // ---- wmod role (one co, all b) ----
        const int co = bid - 1025;
        const int ci = t;
        const int lane = t & 63, wid = t >> 6;
        float as = 0.f;
#pragma unroll
        for (int k = 0; k < 16; ++k) { float sv = s[k * 256 + t]; as += sv * sv; }
        const float* wp = w + ((size_t)co * CIN + ci) * 9;
        float wv[9];
        float q = 0.f;
#pragma unroll
        for (int tp = 0; tp < 9; ++tp) { wv[tp] = wp[tp]; q += wv[tp] * wv[tp]; }
        float a = as, qq = q;
        for (int off = 32; off > 0; off >>= 1) {
            a  += __shfl_down(a,  off, 64);
            qq += __shfl_down(qq, off, 64);
        }
        if (lane == 0) { red[wid] = a; red[4 + wid] = qq; }
        __syncthreads();
        const float ssum = red[0] + red[1] + red[2] + red[3];
        const float Sw   = red[4] + red[5] + red[6] + red[7];
        const float sn2  = (float)(B_ * CIN) / ssum;
        const float wn   = rsqrtf(Sw / 2304.f);
        const float wn2sn2 = wn * wn * sn2;
        const float wsn  = wn * sqrtf(sn2);

        for (int b = 0; b < B_; ++b) {
            const float sv = s[b * CIN + ci];
            float v = sv * sv * q;
            for (int off = 32; off > 0; off >>= 1) v += __shfl_down(v, off, 64);
            __syncthreads();
            if (lane == 0) red[wid] = v;
            __syncthreads();
            const float S = red[0] + red[1] + red[2] + red[3];
            const float coef = wsn * rsqrtf(wn2sn2 * S + EPS);
            const float sc = sv * coef;
            const size_t obase = ((size_t)b * 9) * 65536 + (size_t)(ci >> 5) * 8192
                               + (size_t)co * 32 + (ci & 31);
#pragma unroll
            for (int tap = 0; tap < 9; ++tap)
                wfull[obase + (size_t)tap * 65536] = (__bf16)(wv[tap] * sc);
        }
        return;
    }

    // ---- x transpose role: fp32 NCHW -> bf16 [b][row][col][ci] ----
    const int row = bid & 63;
    const int b   = bid >> 6;
    const float* xbase = x + ((size_t)b * CIN * HW + row) * HW;
#pragma unroll
    for (int k = 0; k < 8; ++k) {
        int p   = k * 256 + t;
        int ci2 = p >> 4;
        int c4  = (p & 15) * 4;
        const float* src = xbase + (size_t)(2 * ci2) * (HW * HW) + c4;
        float4 v0 = *(const float4*)src;
        float4 v1 = *(const float4*)(src + HW * HW);
        const int dj = ci2 + (ci2 >> 2);
#pragma unroll
        for (int i = 0; i < 4; ++i)
            xsd[(c4 + i) * 160 + dj] = pack2((&v0.x)[i], (&v1.x)[i]);
    }
    __syncthreads();
    __bf16* orow = xbf + (((size_t)b * HW + row) * 64) * CIN;
#pragma unroll
    for (int k = 0; k < 8; ++k) {
        int o   = k * 256 + t;
        int col = o >> 5;
        int u   = o & 31;
        const uint* rp = &xsd[col * 160 + 5 * u];
        uint4 vv; vv.x = rp[0]; vv.y = rp[1]; vv.z = rp[2]; vv.w = rp[3];
        *(uint4*)&orow[(size_t)col * CIN + u * 8] = vv;
    }
}

// ================= MFMA implicit-GEMM conv, v8: 2-row blocks =================
// grid 512 (XCD-affine: b = (bid&7)+8*(bid>=256), rowpair = (bid>>3)&31), 4 waves.
// Each block: 2 output rows (128 px) x 256 co. Wave wy = co quarter:
// 64 co x 128 px via acc[4][8]. Per tap: 32 MFMA vs 4 A-loads + 8 B-reads
// (2x the MFMA:overhead ratio of v5). Grid = exactly 2 blocks/CU, uniform.
// LDS x tile (per buf): 4 qq x (4 halo rows x 66 cols) = 1056 slots of 16B;
// slot = qq*264 + irow*66 + col. Staged via 4 full async16 rounds + 8-lane tail.
__global__ __launch_bounds__(256, 2) void conv_mfma4(const __bf16* __restrict__ xbf,
                                                     const __bf16* __restrict__ zrow,
                                                     const __bf16* __restrict__ wfull,
                                                     float* __restrict__ out) {
    __shared__ __attribute__((aligned(16))) __bf16 xs[2][1056 * 8];   // 2 x 16,896 B

    const int bid = blockIdx.x;
    const int b   = (bid & 7) + ((bid >= 256) ? 8 : 0);
    const int r0  = ((bid >> 3) & 31) * 2;
    const int t = threadIdx.x;
    const int wy = t >> 6, lane = t & 63;
    const int m16 = lane & 15, q = lane >> 4;

    // staging sources: issues 0..3: (qq=i, rem=t); issue 4: (qq=wy, rem=256+lane), lane<8
    const __bf16* gsrc[5];
#pragma unroll
    for (int i = 0; i < 5; ++i) {
        int qq, rem;
        if (i < 4) { qq = i;  rem = t; }
        else       { qq = wy; rem = 256 + (lane & 7); }
        int irow = rem / 66;
        int col  = rem - irow * 66;
        int gr   = r0 - 1 + irow;
        if ((unsigned)gr < 64u && col != 0 && col != 65)
            gsrc[i] = xbf + (((size_t)b * HW + gr) * 64 + (col - 1)) * CIN + qq * 8;
        else
            gsrc[i] = zrow + col * CIN + qq * 8;    // zero halo pool
    }

    // prologue: stage chunk 0 into buf 0
#pragma unroll
    for (int i = 0; i < 4; ++i)
        async16((char*)xs[0] + (i * 264 + t) * 16, gsrc[i]);
    if (lane < 8)
        async16((char*)xs[0] + (wy * 264 + 256 + lane) * 16, gsrc[4]);

    f32x4 acc[4][8] = {};
    const __bf16* abase = wfull + (size_t)b * 589824
                        + (size_t)(wy * 64 + m16) * 32 + q * 8;

    bf16x8 afc[4];
#pragma unroll
    for (int i = 0; i < 4; ++i)
        afc[i] = *(const bf16x8*)(abase + i * 512);    // cc=0, tap=0

    for (int cc = 0; cc < 8; ++cc) {
        const __bf16* wb = abase + (size_t)cc * 8192;
        __syncthreads();                       // drains chunk-cc staging
        if (cc < 7) {
            const int d = cc * 32 + 32;
#pragma unroll
            for (int i = 0; i < 4; ++i)
                async16((char*)xs[(cc + 1) & 1] + (i * 264 + t) * 16, gsrc[i] + d);
            if (lane < 8)
                async16((char*)xs[(cc + 1) & 1] + (wy * 264 + 256 + lane) * 16, gsrc[4] + d);
        }
        const __bf16* xcur = xs[cc & 1];
#pragma unroll
        for (int tap = 0; tap < 9; ++tap) {
            const int dr = tap / 3, dc = tap % 3;
            bf16x8 bfr[8];
#pragma unroll
            for (int j = 0; j < 8; ++j) {
                const int slot = q * 264 + ((j >> 2) + dr) * 66 + (j & 3) * 16 + m16 + dc;
                bfr[j] = *(const bf16x8*)&xcur[slot * 8];
            }
            bf16x8 afn[4];
            if (tap < 8) {
#pragma unroll
                for (int i = 0; i < 4; ++i)
                    afn[i] = *(const bf16x8*)(wb + (size_t)(tap + 1) * 65536 + i * 512);
            } else if (cc < 7) {
#pragma unroll
                for (int i = 0; i < 4; ++i)
                    afn[i] = *(const bf16x8*)(wb + 8192 + i * 512);
            }
            __builtin_amdgcn_s_setprio(1);
#pragma unroll
            for (int i = 0; i < 4; ++i)
#pragma unroll
                for (int j = 0; j < 8; ++j)
                    acc[i][j] = __builtin_amdgcn_mfma_f32_16x16x32_bf16(afc[i], bfr[j], acc[i][j], 0, 0, 0);
            __builtin_amdgcn_s_setprio(0);
            if (tap < 8 || cc < 7) {
#pragma unroll
                for (int i = 0; i < 4; ++i) afc[i] = afn[i];
            }
        }
    }

    // epilogue: D col = lane&15 (pixel within 16), row = q*4+reg (co)
    // tile j: out row = r0 + (j>>2), cols (j&3)*16 + m16
#pragma unroll
    for (int i = 0; i < 4; ++i) {
        const int cobase = wy * 64 + i * 16 + q * 4;
#pragma unroll
        for (int reg = 0; reg < 4; ++reg) {
            float* op = out + ((size_t)b * COUT + (cobase + reg)) * (HW * HW) + r0 * HW + m16;
#pragma unroll
            for (int j = 0; j < 8; ++j)
                op[(j >> 2) * HW + (j & 3) * 16] = acc[i][j][reg];
        }
    }
}

extern "C" void kernel_launch(void* const* d_in, const int* in_sizes, int n_in,
                              void* d_out, int out_size, void* d_ws, size_t ws_size,
                              hipStream_t stream) {
    const float* x = (const float*)d_in[0];
    const float* s = (const float*)d_in[1];
    const float* w = (const float*)d_in[2];
    float* out = (float*)d_out;

    float* ws = (float*)d_ws;
    __bf16* wfull = (__bf16*)(ws + 70656);     // 18,874,368 B
    __bf16* zrow  = (__bf16*)(ws + 4789248);   // 36,864 B zero pool
    __bf16* xbf   = (__bf16*)(ws + 4798464);   // 33,554,432 B

    prep_kernel<<<1281, 256, 0, stream>>>(x, s, w, xbf, wfull, zrow);
    conv_mfma4<<<512, 256, 0, stream>>>(xbf, zrow, wfull, out);
}